// Round 4
// baseline (378.164 us; speedup 1.0000x reference)
//
#include <hip/hip_runtime.h>

// Problem constants (from reference setup_inputs)
#define B_  48
#define S_  1024
#define D_  128
#define DK_ 64
#define BS_ (B_ * S_)

typedef _Float16 f16x8 __attribute__((ext_vector_type(8)));
typedef _Float16 f16x4 __attribute__((ext_vector_type(4)));
typedef float    f32x4 __attribute__((ext_vector_type(4)));

__device__ __forceinline__ float fast_exp2(float x) {
#if __has_builtin(__builtin_amdgcn_exp2f)
    return __builtin_amdgcn_exp2f(x);
#else
    return exp2f(x);
#endif
}
__device__ __forceinline__ float fast_rcp(float x) {
#if __has_builtin(__builtin_amdgcn_rcpf)
    return __builtin_amdgcn_rcpf(x);
#else
    return 1.0f / x;
#endif
}

// ---------------------------------------------------------------------------
// K1: Q = query @ Wq, K = query @ Wk in exact fp32 (VALU), stored as fp16
// hi/lo split pairs for split-precision MFMA in K2.
// grid.x = (BS/64)*2  (even blocks: Q, odd blocks: K), 256 threads.
// Each block: 64 rows x 64 cols. Thread tile 4x4. W staged in LDS (fp32).
// Also zeroes sums[] (block 0). Total ws use: 25.2 MB (round-1-proven size;
// round-2's 126 MB ews buffer overran ws and corrupted harness state).
// ---------------------------------------------------------------------------
__global__ __launch_bounds__(256) void qk_proj(
    const float* __restrict__ query,
    const float* __restrict__ Wq, const float* __restrict__ Wk,
    _Float16* __restrict__ Qhi, _Float16* __restrict__ Qlo,
    _Float16* __restrict__ Khi, _Float16* __restrict__ Klo,
    float* __restrict__ sums)
{
    __shared__ float Wl[D_][DK_ + 4];   // pad kills bank conflicts

    const int t  = threadIdx.x;
    const int bx = blockIdx.x;
    const int m  = bx & 1;              // 0 = Q, 1 = K
    const int r0 = (bx >> 1) * 64;
    const float* __restrict__ Wsrc = m ? Wk : Wq;
    _Float16* __restrict__ ohi = m ? Khi : Qhi;
    _Float16* __restrict__ olo = m ? Klo : Qlo;

    if (bx == 0 && t < B_) sums[t] = 0.0f;

    #pragma unroll
    for (int i = 0; i < 8; ++i) {
        int idx = t + i * 256;
        int row = idx >> 4;
        int c4  = (idx & 15) << 2;
        *(float4*)&Wl[row][c4] = *(const float4*)(Wsrc + row * DK_ + c4);
    }
    __syncthreads();

    const int rg = t >> 4;
    const int cg = t & 15;
    const float* __restrict__ qrow = query + (size_t)(r0 + rg * 4) * D_;

    float acc[4][4];
    #pragma unroll
    for (int r = 0; r < 4; ++r)
        #pragma unroll
        for (int c = 0; c < 4; ++c) acc[r][c] = 0.0f;

    for (int k = 0; k < D_; k += 4) {
        float qv[4][4], wv[4][4];
        #pragma unroll
        for (int dr = 0; dr < 4; ++dr) {
            float4 v = *(const float4*)(qrow + (size_t)dr * D_ + k);
            qv[dr][0] = v.x; qv[dr][1] = v.y; qv[dr][2] = v.z; qv[dr][3] = v.w;
        }
        #pragma unroll
        for (int dk = 0; dk < 4; ++dk) {
            float4 v = *(const float4*)&Wl[k + dk][cg * 4];
            wv[dk][0] = v.x; wv[dk][1] = v.y; wv[dk][2] = v.z; wv[dk][3] = v.w;
        }
        #pragma unroll
        for (int dr = 0; dr < 4; ++dr)
            #pragma unroll
            for (int dk = 0; dk < 4; ++dk)
                #pragma unroll
                for (int dc = 0; dc < 4; ++dc)
                    acc[dr][dc] = fmaf(qv[dr][dk], wv[dk][dc], acc[dr][dc]);
    }

    #pragma unroll
    for (int dr = 0; dr < 4; ++dr) {
        f16x4 h, l;
        #pragma unroll
        for (int dc = 0; dc < 4; ++dc) {
            float x = acc[dr][dc];
            _Float16 hi = (_Float16)x;
            h[dc] = hi;
            l[dc] = (_Float16)(x - (float)hi);
        }
        size_t off = (size_t)(r0 + rg * 4 + dr) * DK_ + cg * 4;
        *(f16x4*)(ohi + off) = h;
        *(f16x4*)(olo + off) = l;
    }
}

// ---------------------------------------------------------------------------
// K2: scores = Q·K^T via split-precision fp16 MFMA (3 terms: hh + hl + lh),
// fused tanh->exp epilogue. e = exp(10*tanh(x)-10) (diag=0) stored as fp16
// INSIDE d_out, SELF-OVERWRITING STRIDED layout: output group g = gidx>>11
// (2048 fp32 = 8 KB); chunk t = (gidx&2047)>>3 (8 elems) lives at halves
// g*4096 + 16t .. +8, i.e. group bytes [32t, 32t+16) — the SAME bytes its
// fp32 expansion occupies [32t, 32t+32). In K3 each thread's write covers
// exactly its own source (plus gap); no cross-thread read/write overlap ->
// race-free with no sync. (Round 3's "first 4KB" pack raced cross-wave ->
// fp32 mantissa bits read as fp16 -> NaN.)
// Operands transposed (A=K, B=Q) so D[row=s][col=q]: lane's 4 acc regs are
// 4 consecutive s at fixed q -> one aligned 8B f16x4 store (s0%4==0 keeps
// the 4 values inside one chunk: j&7 in {0,4}).
// grid = (64, 48): 128x128 tile per block. 4 waves (2x2), wave = 64x64 tile.
// ---------------------------------------------------------------------------
__global__ __launch_bounds__(256) void score_sum(
    const _Float16* __restrict__ Qhi, const _Float16* __restrict__ Qlo,
    const _Float16* __restrict__ Khi, const _Float16* __restrict__ Klo,
    float* __restrict__ sums, _Float16* __restrict__ e16 /* = (H*)d_out */)
{
    const int b    = blockIdx.y;
    const int tile = blockIdx.x;
    const int qt   = (tile >> 3) * 128;
    const int st   = (tile & 7) * 128;
    const int t    = threadIdx.x;
    const int lane = t & 63;
    const int wave = t >> 6;
    const int sbase = st + (wave >> 1) * 64;   // rows of D = s
    const int qbase = qt + (wave & 1) * 64;    // cols of D = q
    const int row15 = lane & 15;
    const int quad  = lane >> 4;
    const int koff  = quad * 8;

    const size_t boff = (size_t)b * (S_ * DK_);
    const _Float16* __restrict__ Ah = Khi + boff;
    const _Float16* __restrict__ Al = Klo + boff;
    const _Float16* __restrict__ Bh = Qhi + boff;
    const _Float16* __restrict__ Bl = Qlo + boff;

    f32x4 acc[4][4];
    #pragma unroll
    for (int i = 0; i < 4; ++i)
        #pragma unroll
        for (int j = 0; j < 4; ++j)
            acc[i][j] = (f32x4){0.f, 0.f, 0.f, 0.f};

    #pragma unroll
    for (int kc = 0; kc < 2; ++kc) {
        f16x8 Afh[4], Afl[4], Bfh[4], Bfl[4];
        #pragma unroll
        for (int i = 0; i < 4; ++i) {
            size_t ar = (size_t)(sbase + i * 16 + row15) * DK_ + kc * 32 + koff;
            size_t br = (size_t)(qbase + i * 16 + row15) * DK_ + kc * 32 + koff;
            Afh[i] = *(const f16x8*)(Ah + ar);
            Afl[i] = *(const f16x8*)(Al + ar);
            Bfh[i] = *(const f16x8*)(Bh + br);
            Bfl[i] = *(const f16x8*)(Bl + br);
        }
        #pragma unroll
        for (int rt = 0; rt < 4; ++rt)
            #pragma unroll
            for (int ct = 0; ct < 4; ++ct)
                acc[rt][ct] = __builtin_amdgcn_mfma_f32_16x16x32_f16(
                    Afh[rt], Bfh[ct], acc[rt][ct], 0, 0, 0);
        #pragma unroll
        for (int rt = 0; rt < 4; ++rt)
            #pragma unroll
            for (int ct = 0; ct < 4; ++ct)
                acc[rt][ct] = __builtin_amdgcn_mfma_f32_16x16x32_f16(
                    Afh[rt], Bfl[ct], acc[rt][ct], 0, 0, 0);
        #pragma unroll
        for (int rt = 0; rt < 4; ++rt)
            #pragma unroll
            for (int ct = 0; ct < 4; ++ct)
                acc[rt][ct] = __builtin_amdgcn_mfma_f32_16x16x32_f16(
                    Afl[rt], Bfh[ct], acc[rt][ct], 0, 0, 0);
    }

    const float C2X  = 2.8853900817779268f;    //  2*log2(e)
    const float CEXP = -28.853900817779268f;   // -20*log2(e)

    float lsum = 0.0f;

    #pragma unroll
    for (int rt = 0; rt < 4; ++rt) {
        #pragma unroll
        for (int ct = 0; ct < 4; ++ct) {
            const int q  = qbase + ct * 16 + row15;
            const int s0 = sbase + rt * 16 + quad * 4;
            f16x4 pk;
            #pragma unroll
            for (int v = 0; v < 4; ++v) {
                float x = acc[rt][ct][v];
                float u = fast_exp2(x * C2X);                   // e^(2x)
                float e = fast_exp2(CEXP * fast_rcp(u + 1.0f)); // e^(10tanh-10)
                e = (q == s0 + v) ? 0.0f : e;                   // diag -> exact 0
                lsum += e;
                pk[v] = (_Float16)e;
            }
            // gidx=(b<<20)+(q<<10)+s0; group=(b<<9)+(q>>1);
            // j = gidx&2047 = ((q&1)<<10)+s0; chunk=j>>3; off=j&7=s0&7.
            // strided half addr = group*4096 + chunk*16 + (s0&7):
            size_t ha = ((size_t)b << 21) + (size_t)(q >> 1) * 4096
                      + ((size_t)(((q & 1) << 10) + s0) >> 3) * 16 + (s0 & 7);
            *(f16x4*)(e16 + ha) = pk;                           // 8B store
        }
    }

    #pragma unroll
    for (int o = 32; o > 0; o >>= 1) lsum += __shfl_down(lsum, o);
    __shared__ float wsum[4];
    if (lane == 0) wsum[wave] = lsum;
    __syncthreads();
    if (t == 0) atomicAdd(&sums[b], (wsum[0] + wsum[1]) + (wsum[2] + wsum[3]));
}

// ---------------------------------------------------------------------------
// K3: in-place strided expansion: thread t of group g reads its 8 fp16 at
// halves g*4096 + 16t (group bytes [32t,32t+16)) and writes 8 fp32 at
// g*2048 + 8t (group bytes [32t,32t+32)) — overwrites ONLY its own source.
// Per-lane load->store ordering is a register dependency; no cross-thread
// overlap anywhere. Each block: 4 groups = 8192 elems. grid = 6144 x 256.
// ---------------------------------------------------------------------------
__global__ __launch_bounds__(256) void scale_k(
    float* __restrict__ out, const float* __restrict__ sums)
{
    const int blk = blockIdx.x;
    const int b   = blk >> 7;                 // 128 blocks per batch
    const float s = sums[b];
    const float r = fast_rcp(s);
    const float inv = r * (2.0f - s * r);     // one Newton step -> fp32-exact

    const _Float16* __restrict__ e16 = (const _Float16*)out;
    const int t = threadIdx.x;

    #pragma unroll
    for (int i = 0; i < 4; ++i) {
        const size_t group = (size_t)blk * 4 + i;
        f16x8 ev = *(const f16x8*)(e16 + group * 4096 + (size_t)t * 16);
        float4 o0, o1;
        o0.x = (float)ev[0] * inv; o0.y = (float)ev[1] * inv;
        o0.z = (float)ev[2] * inv; o0.w = (float)ev[3] * inv;
        o1.x = (float)ev[4] * inv; o1.y = (float)ev[5] * inv;
        o1.z = (float)ev[6] * inv; o1.w = (float)ev[7] * inv;
        size_t oidx = group * 2048 + (size_t)t * 8;
        *(float4*)(out + oidx)     = o0;
        *(float4*)(out + oidx + 4) = o1;
    }
}

// ---------------------------------------------------------------------------
extern "C" void kernel_launch(void* const* d_in, const int* in_sizes, int n_in,
                              void* d_out, int out_size, void* d_ws, size_t ws_size,
                              hipStream_t stream)
{
    (void)in_sizes; (void)n_in; (void)out_size; (void)ws_size;
    const float* query = (const float*)d_in[0];
    // d_in[1] (exchange) and d_in[2] (solution_indexes) unused by reference.
    const float* Wq = (const float*)d_in[3];
    const float* Wk = (const float*)d_in[4];
    float* out = (float*)d_out;

    const size_t N = (size_t)BS_ * DK_;   // 3,145,728 halves per array
    _Float16* Qhi = (_Float16*)d_ws;
    _Float16* Qlo = Qhi + N;
    _Float16* Khi = Qlo + N;
    _Float16* Klo = Khi + N;
    float* sums = (float*)(Klo + N);      // 48 floats; ws total ~25.2 MB

    qk_proj<<<dim3((BS_ / 64) * 2), 256, 0, stream>>>(query, Wq, Wk,
                                                      Qhi, Qlo, Khi, Klo, sums);
    dim3 g(64, B_);
    score_sum<<<g, 256, 0, stream>>>(Qhi, Qlo, Khi, Klo, sums, (_Float16*)out);
    scale_k<<<dim3(6144), 256, 0, stream>>>(out, sums);
}

// Round 5
// 322.964 us; speedup vs baseline: 1.1709x; 1.1709x over previous
//
#include <hip/hip_runtime.h>

// Problem constants (from reference setup_inputs)
#define B_  48
#define S_  1024
#define D_  128
#define DK_ 64
#define BS_ (B_ * S_)

typedef _Float16 f16x8 __attribute__((ext_vector_type(8)));
typedef _Float16 f16x4 __attribute__((ext_vector_type(4)));
typedef float    f32x4 __attribute__((ext_vector_type(4)));

__device__ __forceinline__ float fast_exp2(float x) {
#if __has_builtin(__builtin_amdgcn_exp2f)
    return __builtin_amdgcn_exp2f(x);
#else
    return exp2f(x);
#endif
}
__device__ __forceinline__ float fast_rcp(float x) {
#if __has_builtin(__builtin_amdgcn_rcpf)
    return __builtin_amdgcn_rcpf(x);
#else
    return 1.0f / x;
#endif
}

// ---------------------------------------------------------------------------
// K1: Q = query @ Wq, K = query @ Wk in exact fp32 (VALU), stored as fp16
// hi/lo split pairs for split-precision MFMA (2-term: QhKh + QlKh; Klo is
// stored but unused — kept for layout symmetry, ~1 us).
// grid.x = (BS/64)*2 (even: Q, odd: K), 256 thr. Block: 64x64, thread 4x4.
// Also zeroes sums[] (block 0). ws use: 25.2 MB of 768 MiB.
// ---------------------------------------------------------------------------
__global__ __launch_bounds__(256) void qk_proj(
    const float* __restrict__ query,
    const float* __restrict__ Wq, const float* __restrict__ Wk,
    _Float16* __restrict__ Qhi, _Float16* __restrict__ Qlo,
    _Float16* __restrict__ Khi, _Float16* __restrict__ Klo,
    float* __restrict__ sums)
{
    __shared__ float Wl[D_][DK_ + 4];   // pad kills bank conflicts

    const int t  = threadIdx.x;
    const int bx = blockIdx.x;
    const int m  = bx & 1;              // 0 = Q, 1 = K
    const int r0 = (bx >> 1) * 64;
    const float* __restrict__ Wsrc = m ? Wk : Wq;
    _Float16* __restrict__ ohi = m ? Khi : Qhi;
    _Float16* __restrict__ olo = m ? Klo : Qlo;

    if (bx == 0 && t < B_) sums[t] = 0.0f;

    #pragma unroll
    for (int i = 0; i < 8; ++i) {
        int idx = t + i * 256;
        int row = idx >> 4;
        int c4  = (idx & 15) << 2;
        *(float4*)&Wl[row][c4] = *(const float4*)(Wsrc + row * DK_ + c4);
    }
    __syncthreads();

    const int rg = t >> 4;
    const int cg = t & 15;
    const float* __restrict__ qrow = query + (size_t)(r0 + rg * 4) * D_;

    float acc[4][4];
    #pragma unroll
    for (int r = 0; r < 4; ++r)
        #pragma unroll
        for (int c = 0; c < 4; ++c) acc[r][c] = 0.0f;

    for (int k = 0; k < D_; k += 4) {
        float qv[4][4], wv[4][4];
        #pragma unroll
        for (int dr = 0; dr < 4; ++dr) {
            float4 v = *(const float4*)(qrow + (size_t)dr * D_ + k);
            qv[dr][0] = v.x; qv[dr][1] = v.y; qv[dr][2] = v.z; qv[dr][3] = v.w;
        }
        #pragma unroll
        for (int dk = 0; dk < 4; ++dk) {
            float4 v = *(const float4*)&Wl[k + dk][cg * 4];
            wv[dk][0] = v.x; wv[dk][1] = v.y; wv[dk][2] = v.z; wv[dk][3] = v.w;
        }
        #pragma unroll
        for (int dr = 0; dr < 4; ++dr)
            #pragma unroll
            for (int dk = 0; dk < 4; ++dk)
                #pragma unroll
                for (int dc = 0; dc < 4; ++dc)
                    acc[dr][dc] = fmaf(qv[dr][dk], wv[dk][dc], acc[dr][dc]);
    }

    #pragma unroll
    for (int dr = 0; dr < 4; ++dr) {
        f16x4 h, l;
        #pragma unroll
        for (int dc = 0; dc < 4; ++dc) {
            float x = acc[dr][dc];
            _Float16 hi = (_Float16)x;
            h[dc] = hi;
            l[dc] = (_Float16)(x - (float)hi);
        }
        size_t off = (size_t)(r0 + rg * 4 + dr) * DK_ + cg * 4;
        *(f16x4*)(ohi + off) = h;
        *(f16x4*)(olo + off) = l;
    }
}

// ---------------------------------------------------------------------------
// K2: scores = Q·K^T via 2-term split fp16 MFMA (QhiKhi + QloKhi; residual
// QhiKlo gives score err ~1e-3 rms -> prob err ~1e-8, under 4.65e-8 thr),
// fused e = exp(10*tanh(x)-10) epilogue (diag = exact 0).
//   WRITE=false: per-batch sum of e -> one atomicAdd per block (no stores).
//   WRITE=true : recompute, write out = e/sum[b] as fp32, COALESCED —
//     orientation A=Q (rows=q), B=K (cols=s): C/D layout col=lane&15=s,
//     row=quad*4+reg=q, so each scalar store instr = 4 perfect 64B segments.
//     (Round 4 stored an fp16 intermediate in d_out; its strided in-place
//     expansion fetched 2x lines — recompute + direct write is cheaper.)
// grid = (64, 48): 128x128 tile/block, 4 waves (2x2), wave = 64x64 tile.
// e via 2^(-20*log2e / (2^(2x*log2e) + 1)); exact at +-inf, NaN-free.
// ---------------------------------------------------------------------------
template <bool WRITE>
__global__ __launch_bounds__(256) void score_k(
    const _Float16* __restrict__ Qhi, const _Float16* __restrict__ Qlo,
    const _Float16* __restrict__ Khi,
    float* __restrict__ sums, float* __restrict__ out)
{
    const int b    = blockIdx.y;
    const int tile = blockIdx.x;
    const int qt   = (tile >> 3) * 128;
    const int st   = (tile & 7) * 128;
    const int t    = threadIdx.x;
    const int lane = t & 63;
    const int wave = t >> 6;
    const int qbase = qt + (wave >> 1) * 64;   // A-side rows = q
    const int sbase = st + (wave & 1) * 64;    // B-side rows = s (cols of D)
    const int row15 = lane & 15;
    const int quad  = lane >> 4;
    const int koff  = quad * 8;

    const size_t boff = (size_t)b * (S_ * DK_);
    const _Float16* __restrict__ Ah = Qhi + boff;
    const _Float16* __restrict__ Al = Qlo + boff;
    const _Float16* __restrict__ Bh = Khi + boff;

    f32x4 acc[4][4];
    #pragma unroll
    for (int i = 0; i < 4; ++i)
        #pragma unroll
        for (int j = 0; j < 4; ++j)
            acc[i][j] = (f32x4){0.f, 0.f, 0.f, 0.f};

    #pragma unroll
    for (int kc = 0; kc < 2; ++kc) {
        f16x8 Afh[4], Afl[4], Bfh[4];
        #pragma unroll
        for (int i = 0; i < 4; ++i) {
            size_t ar = (size_t)(qbase + i * 16 + row15) * DK_ + kc * 32 + koff;
            size_t br = (size_t)(sbase + i * 16 + row15) * DK_ + kc * 32 + koff;
            Afh[i] = *(const f16x8*)(Ah + ar);
            Afl[i] = *(const f16x8*)(Al + ar);
            Bfh[i] = *(const f16x8*)(Bh + br);
        }
        #pragma unroll
        for (int rt = 0; rt < 4; ++rt)
            #pragma unroll
            for (int ct = 0; ct < 4; ++ct)
                acc[rt][ct] = __builtin_amdgcn_mfma_f32_16x16x32_f16(
                    Afh[rt], Bfh[ct], acc[rt][ct], 0, 0, 0);
        #pragma unroll
        for (int rt = 0; rt < 4; ++rt)
            #pragma unroll
            for (int ct = 0; ct < 4; ++ct)
                acc[rt][ct] = __builtin_amdgcn_mfma_f32_16x16x32_f16(
                    Afl[rt], Bfh[ct], acc[rt][ct], 0, 0, 0);
    }

    const float C2X  = 2.8853900817779268f;    //  2*log2(e)
    const float CEXP = -28.853900817779268f;   // -20*log2(e)

    float lsum = 0.0f;
    float inv  = 0.0f;
    float* __restrict__ outb = nullptr;
    if (WRITE) {
        float sv = sums[b];
        float r  = fast_rcp(sv);
        inv  = r * (2.0f - sv * r);            // Newton -> fp32-exact divide
        outb = out + ((size_t)b << 20);
    }

    #pragma unroll
    for (int rt = 0; rt < 4; ++rt) {
        #pragma unroll
        for (int ct = 0; ct < 4; ++ct) {
            const int s  = sbase + ct * 16 + row15;
            const int q0 = qbase + rt * 16 + quad * 4;
            #pragma unroll
            for (int v = 0; v < 4; ++v) {
                const int q = q0 + v;
                float x = acc[rt][ct][v];
                float u = fast_exp2(x * C2X);                   // e^(2x)
                float e = fast_exp2(CEXP * fast_rcp(u + 1.0f)); // e^(10tanh-10)
                e = (q == s) ? 0.0f : e;                        // diag -> 0
                if (WRITE) {
                    outb[((size_t)q << 10) + s] = e * inv;      // coalesced
                } else {
                    lsum += e;
                }
            }
        }
    }

    if (!WRITE) {
        #pragma unroll
        for (int o = 32; o > 0; o >>= 1) lsum += __shfl_down(lsum, o);
        __shared__ float wsum[4];
        if (lane == 0) wsum[wave] = lsum;
        __syncthreads();
        if (t == 0) atomicAdd(&sums[b], (wsum[0] + wsum[1]) + (wsum[2] + wsum[3]));
    }
}

// ---------------------------------------------------------------------------
extern "C" void kernel_launch(void* const* d_in, const int* in_sizes, int n_in,
                              void* d_out, int out_size, void* d_ws, size_t ws_size,
                              hipStream_t stream)
{
    (void)in_sizes; (void)n_in; (void)out_size; (void)ws_size;
    const float* query = (const float*)d_in[0];
    // d_in[1] (exchange) and d_in[2] (solution_indexes) unused by reference.
    const float* Wq = (const float*)d_in[3];
    const float* Wk = (const float*)d_in[4];
    float* out = (float*)d_out;

    const size_t N = (size_t)BS_ * DK_;   // 3,145,728 halves per array
    _Float16* Qhi = (_Float16*)d_ws;
    _Float16* Qlo = Qhi + N;
    _Float16* Khi = Qlo + N;
    _Float16* Klo = Khi + N;
    float* sums = (float*)(Klo + N);      // 48 floats; ws total ~25.2 MB

    qk_proj<<<dim3((BS_ / 64) * 2), 256, 0, stream>>>(query, Wq, Wk,
                                                      Qhi, Qlo, Khi, Klo, sums);
    dim3 g(64, B_);
    score_k<false><<<g, 256, 0, stream>>>(Qhi, Qlo, Khi, sums, nullptr);
    score_k<true><<<g, 256, 0, stream>>>(Qhi, Qlo, Khi, sums, out);
}